// Round 19
// baseline (60.161 us; speedup 1.0000x reference)
//
#include <hip/hip_runtime.h>
#include <hip/hip_cooperative_groups.h>
#include <math.h>

namespace cg = cooperative_groups;

#define MS 256
#define KV 64
#define HPX (1.0f / 256.0f)
#define TK 288539.0083f            // 2 * 100000 * log2(e)
#define TAUE 1.2e-4f               // |cr| beyond this: d2 < 2^-34

__global__ __launch_bounds__(256) void cdm_fused(
    const float* __restrict__ contour,   // (bn, KV, 2)
    float* __restrict__ out,             // (bn, 256, 256) final dmap
    float* __restrict__ bmax)            // per-block max scratch
{
    __shared__ __align__(16) float2 vlds[KV + 2];  // vertices + wrap
    __shared__ int   evt[4][MS + 1];               // winding interval endpoints
    __shared__ float corr[4][MS];                  // tanh-deviation scatter
    __shared__ int   part[4][4];
    __shared__ float wmax[4];

    const int bn = blockIdx.x >> 6;          // image (64 column-quads each)
    const int cq = blockIdx.x & 63;
    const float mx0 = (float)(4 * cq) * HPX;
    const float mx1 = mx0 + HPX;
    const float mx2 = mx0 + 2.0f * HPX;
    const float mx3 = mx0 + 3.0f * HPX;
    const int tid = threadIdx.x;

    for (int i = tid; i < 4 * (MS + 1); i += 256) ((int*)evt)[i] = 0;
    for (int i = tid; i < 4 * MS; i += 256) ((float*)corr)[i] = 0.0f;

    const float2* gsrc = (const float2*)contour + bn * KV;
    if (tid < KV) vlds[tid] = gsrc[tid];
    if (tid == 0) vlds[KV] = gsrc[0];
    __syncthreads();

    // ---- scatter: 256 tasks = 64 edges x 4 columns ----
    {
        const int e = tid & 63;
        const int c = tid >> 6;
        const float mx = mx0 + (float)c * HPX;
        const float2 A = vlds[e];
        const float2 B = vlds[e + 1];
        const float C1 = B.x - A.x;                     // cr(my) = C0 - my*C1
        const float C0 = fmaf(A.y, B.x, -(A.x * B.y)) + mx * (B.y - A.y);
        const bool  up = B.y > A.y;
        const float lo = fminf(A.y, B.y);
        const float hi = fmaxf(A.y, B.y);
        const float y0 = C0 * __builtin_amdgcn_rcpf(C1);   // may be +-inf/NaN

        // winding interval: up needs cr<0, down needs cr>=0
        const bool cut_low = (up == (C1 > 0.0f));
        const float l = cut_low ? fmaxf(lo, y0) : lo;
        const float h = cut_low ? hi : fminf(hi, y0);
        if (l < h) {
            const int jl = (int)ceilf(fminf(fmaxf(l * 256.0f, 0.0f), 256.0f));
            const int jh = (int)ceilf(fminf(fmaxf(h * 256.0f, 0.0f), 256.0f));
            if (jl < jh) {
                const int dir = up ? 1 : -1;
                atomicAdd(&evt[c][jl], dir);
                atomicAdd(&evt[c][jh], -dir);
            }
        }

        // corr scatter: rows with |cr| < TAUE, exact dot<0 gate
        const float aC1 = __builtin_fabsf(C1);
        float wf = TAUE * __builtin_amdgcn_rcpf(aC1) * 256.0f;  // half-width in rows
        const bool full = !(wf < 300.0f);                       // near-vertical
        const float y0c = fminf(fmaxf(y0, -4.0f), 4.0f);        // NaN-safe
        const int W  = (int)fminf(wf, 300.0f) + 1;
        const int jc = (int)(y0c * 256.0f);
        const int sl = (int)ceilf(lo * 256.0f) - 1;
        const int sh = (int)(hi * 256.0f) + 1;
        int j0 = full ? max(sl, 0) : max(max(jc - W, sl), 0);
        int j1 = full ? min(sh, 255) : min(min(jc + W, sh), 255);
        for (int j = j0; j <= j1; ++j) {
            const float my = (float)j * HPX;
            const float cr = fmaf(-my, C1, C0);
            const float acr = __builtin_fabsf(cr);
            if (acr < TAUE) {
                const float dot = fmaf(A.x - mx, B.x - mx, (A.y - my) * (B.y - my));
                if (dot < 0.0f) {
                    const float e2 = __builtin_amdgcn_exp2f(acr * TK);
                    const float d2 = __builtin_amdgcn_rcpf(e2 + 1.0f);
                    atomicAdd(&corr[c][j], __builtin_copysignf(d2, cr));
                }
            }
        }
    }
    __syncthreads();

    // ---- per-column inclusive prefix scan of evt -> exact winding ----
    int v0 = evt[0][tid];
    int v1 = evt[1][tid];
    int v2 = evt[2][tid];
    int v3 = evt[3][tid];
    const int lane = tid & 63;
    const int wv = tid >> 6;
    #pragma unroll
    for (int off = 1; off < 64; off <<= 1) {
        const int t0 = __shfl_up(v0, off);
        const int t1 = __shfl_up(v1, off);
        const int t2 = __shfl_up(v2, off);
        const int t3 = __shfl_up(v3, off);
        if (lane >= off) { v0 += t0; v1 += t1; v2 += t2; v3 += t3; }
    }
    if (lane == 63) { part[0][wv] = v0; part[1][wv] = v1;
                      part[2][wv] = v2; part[3][wv] = v3; }
    __syncthreads();
    #pragma unroll
    for (int w = 0; w < 3; ++w)
        if (wv > w) { v0 += part[0][w]; v1 += part[1][w];
                      v2 += part[2][w]; v3 += part[3][w]; }

    // ---- dense part: min distance to 64 vertices, 4 columns share (Vy-my)^2 ----
    const float my = (float)tid * HPX;
    float md0 = 1e30f, md1 = 1e30f, md2 = 1e30f, md3 = 1e30f;
    const float4* vp = (const float4*)vlds;
    #pragma unroll 8
    for (int k = 0; k < KV / 2; ++k) {
        const float4 q = vp[k];
        float t, s;
        t = q.y - my; t = t * t;
        s = q.x - mx0; md0 = fminf(md0, fmaf(s, s, t));
        s = q.x - mx1; md1 = fminf(md1, fmaf(s, s, t));
        s = q.x - mx2; md2 = fminf(md2, fmaf(s, s, t));
        s = q.x - mx3; md3 = fminf(md3, fmaf(s, s, t));
        t = q.w - my; t = t * t;
        s = q.z - mx0; md0 = fminf(md0, fmaf(s, s, t));
        s = q.z - mx1; md1 = fminf(md1, fmaf(s, s, t));
        s = q.z - mx2; md2 = fminf(md2, fmaf(s, s, t));
        s = q.z - mx3; md3 = fminf(md3, fmaf(s, s, t));
    }

    const float r0 = __builtin_fabsf((float)v0 + corr[0][tid]);
    const float r1 = __builtin_fabsf((float)v1 + corr[1][tid]);
    const float r2 = __builtin_fabsf((float)v2 + corr[2][tid]);
    const float r3 = __builtin_fabsf((float)v3 + corr[3][tid]);
    const float pv0 = r0 * __builtin_amdgcn_sqrtf(md0);
    const float pv1 = r1 * __builtin_amdgcn_sqrtf(md1);
    const float pv2 = r2 * __builtin_amdgcn_sqrtf(md2);
    const float pv3 = r3 * __builtin_amdgcn_sqrtf(md3);

    // per-block max -> bmax
    float m = fmaxf(fmaxf(pv0, pv1), fmaxf(pv2, pv3));
    #pragma unroll
    for (int off = 32; off > 0; off >>= 1)
        m = fmaxf(m, __shfl_xor(m, off));
    if (lane == 0) wmax[wv] = m;
    __syncthreads();
    if (tid == 0)
        bmax[blockIdx.x] = fmaxf(fmaxf(wmax[0], wmax[1]), fmaxf(wmax[2], wmax[3]));

    // ---- grid-wide sync; then every block reduces bmax locally ----
    cg::this_grid().sync();

    const int nb = gridDim.x;
    float g = 0.0f;
    for (int i = tid; i < nb; i += 256) g = fmaxf(g, bmax[i]);
    #pragma unroll
    for (int off = 32; off > 0; off >>= 1)
        g = fmaxf(g, __shfl_xor(g, off));
    __syncthreads();                       // wmax reuse safe
    if (lane == 0) wmax[wv] = g;
    __syncthreads();
    const float gm  = fmaxf(fmaxf(wmax[0], wmax[1]), fmaxf(wmax[2], wmax[3]));
    const float inv = __builtin_amdgcn_rcpf(gm);

    // single, final write of the output (register-resident until now)
    float* ob = out + bn * (MS * MS) + (4 * cq) * MS;
    ob[tid]          = pv0 * inv;
    ob[MS + tid]     = pv1 * inv;
    ob[2 * MS + tid] = pv2 * inv;
    ob[3 * MS + tid] = pv3 * inv;
}

extern "C" void kernel_launch(void* const* d_in, const int* in_sizes, int n_in,
                              void* d_out, int out_size, void* d_ws, size_t ws_size,
                              hipStream_t stream) {
    const float* contour = (const float*)d_in[0];
    float* out  = (float*)d_out;
    float* bmax = (float*)d_ws;

    const int bn = in_sizes[0] / (KV * 2);            // 8
    const int nb = bn * 64;                           // 512 (4 columns/block)

    void* args[] = { (void*)&contour, (void*)&out, (void*)&bmax };
    hipLaunchCooperativeKernel((void*)cdm_fused, dim3(nb), dim3(256),
                               args, 0, stream);
}

// Round 20
// 16.036 us; speedup vs baseline: 3.7517x; 3.7517x over previous
//
#include <hip/hip_runtime.h>
#include <math.h>

#define MS 256
#define KV 64
#define HPX (1.0f / 256.0f)
#define TK 288539.0083f            // 2 * 100000 * log2(e)
#define TAUE 1.2e-4f               // |cr| beyond this: d2 < 2^-34

__global__ __launch_bounds__(256) void cdm_pass1(
    const float* __restrict__ contour,   // (bn, KV, 2)
    float* __restrict__ out,             // (bn, 256, 256) unnormalized prod
    float* __restrict__ bmax)            // per-block max (no atomics)
{
    __shared__ __align__(16) float2 vlds[KV + 2];  // vertices + wrap
    __shared__ int   evt[4][MS + 1];               // winding interval endpoints
    __shared__ float corr[4][MS];                  // tanh-deviation scatter
    __shared__ int   part[4][4];
    __shared__ float wmax[4];

    const int bn = blockIdx.x >> 6;          // image (64 column-quads each)
    const int cq = blockIdx.x & 63;
    const float mx0 = (float)(4 * cq) * HPX;
    const float mx1 = mx0 + HPX;
    const float mx2 = mx0 + 2.0f * HPX;
    const float mx3 = mx0 + 3.0f * HPX;
    const int tid = threadIdx.x;

    for (int i = tid; i < 4 * (MS + 1); i += 256) ((int*)evt)[i] = 0;
    for (int i = tid; i < 4 * MS; i += 256) ((float*)corr)[i] = 0.0f;

    const float2* gsrc = (const float2*)contour + bn * KV;
    if (tid < KV) vlds[tid] = gsrc[tid];
    if (tid == 0) vlds[KV] = gsrc[0];
    __syncthreads();

    // ---- scatter: 256 tasks = 64 edges x 4 columns ----
    {
        const int e = tid & 63;
        const int c = tid >> 6;
        const float mx = mx0 + (float)c * HPX;
        const float2 A = vlds[e];
        const float2 B = vlds[e + 1];
        const float C1 = B.x - A.x;                     // cr(my) = C0 - my*C1
        const float C0 = fmaf(A.y, B.x, -(A.x * B.y)) + mx * (B.y - A.y);
        const bool  up = B.y > A.y;
        const float lo = fminf(A.y, B.y);
        const float hi = fmaxf(A.y, B.y);
        const float y0 = C0 * __builtin_amdgcn_rcpf(C1);   // may be +-inf/NaN

        // winding interval: up needs cr<0, down needs cr>=0
        const bool cut_low = (up == (C1 > 0.0f));
        const float l = cut_low ? fmaxf(lo, y0) : lo;
        const float h = cut_low ? hi : fminf(hi, y0);
        if (l < h) {
            const int jl = (int)ceilf(fminf(fmaxf(l * 256.0f, 0.0f), 256.0f));
            const int jh = (int)ceilf(fminf(fmaxf(h * 256.0f, 0.0f), 256.0f));
            if (jl < jh) {
                const int dir = up ? 1 : -1;
                atomicAdd(&evt[c][jl], dir);
                atomicAdd(&evt[c][jh], -dir);
            }
        }

        // corr scatter: rows with |cr| < TAUE, exact dot<0 gate
        const float aC1 = __builtin_fabsf(C1);
        float wf = TAUE * __builtin_amdgcn_rcpf(aC1) * 256.0f;  // half-width in rows
        const bool full = !(wf < 300.0f);                       // near-vertical
        const float y0c = fminf(fmaxf(y0, -4.0f), 4.0f);        // NaN-safe
        const int W  = (int)fminf(wf, 300.0f) + 1;
        const int jc = (int)(y0c * 256.0f);
        const int sl = (int)ceilf(lo * 256.0f) - 1;
        const int sh = (int)(hi * 256.0f) + 1;
        int j0 = full ? max(sl, 0) : max(max(jc - W, sl), 0);
        int j1 = full ? min(sh, 255) : min(min(jc + W, sh), 255);
        for (int j = j0; j <= j1; ++j) {
            const float my = (float)j * HPX;
            const float cr = fmaf(-my, C1, C0);
            const float acr = __builtin_fabsf(cr);
            if (acr < TAUE) {
                const float dot = fmaf(A.x - mx, B.x - mx, (A.y - my) * (B.y - my));
                if (dot < 0.0f) {
                    const float e2 = __builtin_amdgcn_exp2f(acr * TK);
                    const float d2 = __builtin_amdgcn_rcpf(e2 + 1.0f);
                    atomicAdd(&corr[c][j], __builtin_copysignf(d2, cr));
                }
            }
        }
    }
    __syncthreads();

    // ---- per-column inclusive prefix scan of evt -> exact winding ----
    int v0 = evt[0][tid];
    int v1 = evt[1][tid];
    int v2 = evt[2][tid];
    int v3 = evt[3][tid];
    const int lane = tid & 63;
    const int wv = tid >> 6;
    #pragma unroll
    for (int off = 1; off < 64; off <<= 1) {
        const int t0 = __shfl_up(v0, off);
        const int t1 = __shfl_up(v1, off);
        const int t2 = __shfl_up(v2, off);
        const int t3 = __shfl_up(v3, off);
        if (lane >= off) { v0 += t0; v1 += t1; v2 += t2; v3 += t3; }
    }
    if (lane == 63) { part[0][wv] = v0; part[1][wv] = v1;
                      part[2][wv] = v2; part[3][wv] = v3; }
    __syncthreads();
    #pragma unroll
    for (int w = 0; w < 3; ++w)
        if (wv > w) { v0 += part[0][w]; v1 += part[1][w];
                      v2 += part[2][w]; v3 += part[3][w]; }

    // ---- dense part: min distance to 64 vertices, 4 columns share (Vy-my)^2 ----
    const float my = (float)tid * HPX;
    float md0 = 1e30f, md1 = 1e30f, md2 = 1e30f, md3 = 1e30f;
    const float4* vp = (const float4*)vlds;
    #pragma unroll 8
    for (int k = 0; k < KV / 2; ++k) {
        const float4 q = vp[k];
        float t, s;
        t = q.y - my; t = t * t;
        s = q.x - mx0; md0 = fminf(md0, fmaf(s, s, t));
        s = q.x - mx1; md1 = fminf(md1, fmaf(s, s, t));
        s = q.x - mx2; md2 = fminf(md2, fmaf(s, s, t));
        s = q.x - mx3; md3 = fminf(md3, fmaf(s, s, t));
        t = q.w - my; t = t * t;
        s = q.z - mx0; md0 = fminf(md0, fmaf(s, s, t));
        s = q.z - mx1; md1 = fminf(md1, fmaf(s, s, t));
        s = q.z - mx2; md2 = fminf(md2, fmaf(s, s, t));
        s = q.z - mx3; md3 = fminf(md3, fmaf(s, s, t));
    }

    const float r0 = __builtin_fabsf((float)v0 + corr[0][tid]);
    const float r1 = __builtin_fabsf((float)v1 + corr[1][tid]);
    const float r2 = __builtin_fabsf((float)v2 + corr[2][tid]);
    const float r3 = __builtin_fabsf((float)v3 + corr[3][tid]);
    const float pv0 = r0 * __builtin_amdgcn_sqrtf(md0);
    const float pv1 = r1 * __builtin_amdgcn_sqrtf(md1);
    const float pv2 = r2 * __builtin_amdgcn_sqrtf(md2);
    const float pv3 = r3 * __builtin_amdgcn_sqrtf(md3);

    float* ob = out + bn * (MS * MS) + (4 * cq) * MS;
    ob[tid] = pv0;
    ob[MS + tid] = pv1;
    ob[2 * MS + tid] = pv2;
    ob[3 * MS + tid] = pv3;

    // block max -> plain store (no global atomic)
    float m = fmaxf(fmaxf(pv0, pv1), fmaxf(pv2, pv3));
    #pragma unroll
    for (int off = 32; off > 0; off >>= 1)
        m = fmaxf(m, __shfl_xor(m, off));
    if (lane == 0) wmax[wv] = m;
    __syncthreads();
    if (tid == 0)
        bmax[blockIdx.x] = fmaxf(fmaxf(wmax[0], wmax[1]), fmaxf(wmax[2], wmax[3]));
}

__global__ __launch_bounds__(256) void cdm_pass2(
    float4* __restrict__ out, const float* __restrict__ bmax, int nb, int n4)
{
    float m = 0.0f;
    for (int i = threadIdx.x; i < nb; i += 256) m = fmaxf(m, bmax[i]);
    #pragma unroll
    for (int off = 32; off > 0; off >>= 1)
        m = fmaxf(m, __shfl_xor(m, off));

    __shared__ float wm[4];
    if ((threadIdx.x & 63) == 0) wm[threadIdx.x >> 6] = m;
    __syncthreads();
    const float gm  = fmaxf(fmaxf(wm[0], wm[1]), fmaxf(wm[2], wm[3]));
    const float inv = 1.0f / gm;

    const int i = blockIdx.x * 256 + threadIdx.x;
    if (i < n4) {
        float4 v = out[i];
        v.x *= inv; v.y *= inv; v.z *= inv; v.w *= inv;
        out[i] = v;
    }
}

extern "C" void kernel_launch(void* const* d_in, const int* in_sizes, int n_in,
                              void* d_out, int out_size, void* d_ws, size_t ws_size,
                              hipStream_t stream) {
    const float* contour = (const float*)d_in[0];
    float* out  = (float*)d_out;
    float* bmax = (float*)d_ws;

    const int bn = in_sizes[0] / (KV * 2);            // 8
    const int npix = bn * MS * MS;                    // 524288 == out_size

    const int nb = bn * 64;                           // 512 (4 columns/block)
    cdm_pass1<<<nb, 256, 0, stream>>>(contour, out, bmax);

    const int n4 = npix / 4;
    cdm_pass2<<<(n4 + 255) / 256, 256, 0, stream>>>((float4*)out, bmax, nb, n4);
}